// Round 14
// baseline (62.354 us; speedup 1.0000x reference)
//
#include <hip/hip_runtime.h>
#include <hip/hip_bf16.h>

typedef float f32x4 __attribute__((ext_vector_type(4)));
typedef float f32x16 __attribute__((ext_vector_type(16)));
typedef short bf16x8 __attribute__((ext_vector_type(8)));

#define LRELU_SLOPE 0.2f
#define SQRT2F 1.4142135623730951f
#define MODSCALE 0.044194173824159216f  // 512^-0.5

#define GLL(SRC, DST)                                                       \
  __builtin_amdgcn_global_load_lds(                                         \
      (const __attribute__((address_space(1))) unsigned int*)(SRC),         \
      (__attribute__((address_space(3))) unsigned int*)(DST), 16, 0, 0)

// ---------- kernel 1: fused prep: wprep (blocks 0..1023) + style (1024..1151)
//            + xsp border zero (1152..1415) ----------
// wt2 layout: [t][kchunk c(8)][kg(2)][co(512)][ci32] bf16 (slab = 32 KB).
__global__ __launch_bounds__(256) void prep_kernel(const float* __restrict__ w,
                                                   const float* __restrict__ y,
                                                   const float* __restrict__ mw,
                                                   const float* __restrict__ bias,
                                                   __hip_bfloat16* __restrict__ wt2,
                                                   float* __restrict__ wsq,
                                                   float* __restrict__ s,
                                                   __hip_bfloat16* __restrict__ xsp) {
  const int bid = blockIdx.x;
  const int tid = threadIdx.x;
  if (bid < 1024) {  // ---- weight prep ----
    int idx = bid * 256 + tid;  // co*512+ci
    int co = idx >> 9, ci = idx & 511;
    const float* p = w + (size_t)idx * 9;
    float v[9];
    float sq = 0.f;
#pragma unroll
    for (int t = 0; t < 9; ++t) {
      v[t] = p[t];
      sq += v[t] * v[t];
    }
    wsq[idx] = sq;
    int slabbase = ((ci >> 6) * 2 + ((ci >> 5) & 1)) * 16384 + co * 32 + (ci & 31);
#pragma unroll
    for (int t = 0; t < 9; ++t)
      wt2[t * 262144 + slabbase] = __float2bfloat16(v[t]);
  } else if (bid < 1152) {  // ---- style ----
    int l = tid & 63;
    int ci = (bid - 1024) * 4 + (tid >> 6);
    const float4* mwr = reinterpret_cast<const float4*>(mw + ci * 512);
    float4 m0 = mwr[2 * l], m1 = mwr[2 * l + 1];
    float acc[8];
#pragma unroll
    for (int b = 0; b < 8; ++b) {
      const float4* yr = reinterpret_cast<const float4*>(y + b * 512);
      float4 y0 = yr[2 * l], y1 = yr[2 * l + 1];
      acc[b] = m0.x * y0.x + m0.y * y0.y + m0.z * y0.z + m0.w * y0.w +
               m1.x * y1.x + m1.y * y1.y + m1.z * y1.z + m1.w * y1.w;
    }
#pragma unroll
    for (int off = 32; off > 0; off >>= 1) {
#pragma unroll
      for (int b = 0; b < 8; ++b) acc[b] += __shfl_xor(acc[b], off, 64);
    }
    if (l < 8) {
      float v = acc[l] * MODSCALE + bias[ci];
      v = v > 0.f ? v : LRELU_SLOPE * v;
      s[l * 512 + ci] = v * SQRT2F;
    }
  } else {  // ---- zero the 1-px halo border of xsp ----
    int i = (bid - 1152) * 256 + tid;
    int b = i / 8448;
    int r = i - b * 8448;
    int pos = r >> 6;
    int cj = (r & 63) << 3;
    int hr, hc;
    if (pos < 34) { hr = 0; hc = pos; }
    else if (pos < 68) { hr = 33; hc = pos - 34; }
    else if (pos < 100) { hr = pos - 67; hc = 0; }
    else { hr = pos - 99; hc = 33; }
    unsigned off = (unsigned)((b * 34 + hr) * 34 + hc) * 512 + cj;
    int4 z = {0, 0, 0, 0};
    *reinterpret_cast<int4*>(xsp + off) = z;
  }
}

// ---------- kernel 2: fused xs (blocks 0..2047) + demod (2048..2175) ----------
__global__ __launch_bounds__(256) void xsdem_kernel(const float* __restrict__ x,
                                                    const float* __restrict__ s,
                                                    const float* __restrict__ wsq,
                                                    __hip_bfloat16* __restrict__ xsp,
                                                    float* __restrict__ d) {
  const int bid = blockIdx.x;
  const int tid = threadIdx.x;
  if (bid < 2048) {
    int cc = bid & 7;
    int h = (bid >> 3) & 31;
    int b = bid >> 8;
    __shared__ __hip_bfloat16 tile[32][72];
    int cil = tid >> 2;
    int w0 = (tid & 3) * 8;
    int ci = cc * 64 + cil;
    const float* xp = x + (((size_t)(b * 512 + ci) * 32 + h) << 5) + w0;
    float sv = s[b * 512 + ci];
    float4 a0 = *reinterpret_cast<const float4*>(xp);
    float4 a1 = *reinterpret_cast<const float4*>(xp + 4);
    tile[w0 + 0][cil] = __float2bfloat16(a0.x * sv);
    tile[w0 + 1][cil] = __float2bfloat16(a0.y * sv);
    tile[w0 + 2][cil] = __float2bfloat16(a0.z * sv);
    tile[w0 + 3][cil] = __float2bfloat16(a0.w * sv);
    tile[w0 + 4][cil] = __float2bfloat16(a1.x * sv);
    tile[w0 + 5][cil] = __float2bfloat16(a1.y * sv);
    tile[w0 + 6][cil] = __float2bfloat16(a1.z * sv);
    tile[w0 + 7][cil] = __float2bfloat16(a1.w * sv);
    __syncthreads();
    int wloc = tid >> 3;
    int cj = (tid & 7) * 8;
    int4 v = *reinterpret_cast<const int4*>(&tile[wloc][cj]);
    unsigned off = (unsigned)((b * 34 + h + 1) * 34 + (wloc + 1)) * 512 + cc * 64 + cj;
    *reinterpret_cast<int4*>(xsp + off) = v;
  } else {
    int l = tid & 63;
    int co = (bid - 2048) * 4 + (tid >> 6);
    const float4* qr = reinterpret_cast<const float4*>(wsq + co * 512);
    float4 q0 = qr[2 * l], q1 = qr[2 * l + 1];
    float acc[8];
#pragma unroll
    for (int b = 0; b < 8; ++b) {
      const float4* sr = reinterpret_cast<const float4*>(s + b * 512);
      float4 s0 = sr[2 * l], s1 = sr[2 * l + 1];
      acc[b] = q0.x * s0.x * s0.x + q0.y * s0.y * s0.y + q0.z * s0.z * s0.z +
               q0.w * s0.w * s0.w + q1.x * s1.x * s1.x + q1.y * s1.y * s1.y +
               q1.z * s1.z * s1.z + q1.w * s1.w * s1.w;
    }
#pragma unroll
    for (int off = 32; off > 0; off >>= 1) {
#pragma unroll
      for (int b = 0; b < 8; ++b) acc[b] += __shfl_xor(acc[b], off, 64);
    }
    if (l < 8) d[l * 512 + co] = rsqrtf(acc[l] + 1e-8f);
  }
}

// ---------- kernel 3: conv — r12 structure, MFMA shape 32x32x16 (A/B test) ----------
// 8 waves, K-split kg; per wave 64pix x 64co as 2x2 f32x16 accs; B direct global->reg.
__global__ __launch_bounds__(512, 2) void conv_kernel(const __hip_bfloat16* __restrict__ xsp,
                                                      const __hip_bfloat16* __restrict__ wt2,
                                                      const float* __restrict__ dmod,
                                                      float* __restrict__ out) {
  __shared__ __hip_bfloat16 As_[2][224 * 64];  // 2 x 28 KB
  __shared__ float red[16384];                 // 64 KB reduction buffer
  const int bid = blockIdx.x;
  const int xcd = bid & 7, slot0 = bid >> 3;
  const int bm = xcd * 8 + (slot0 >> 2);
  const int bn = slot0 & 3;
  const int tid = threadIdx.x;
  const int wv = tid >> 6;
  const int l = tid & 63;
  const int kg = wv >> 2;
  const int wr = (wv >> 1) & 1, wc = wv & 1;
  const int bb = bm >> 3;
  const int h0 = (bm & 7) << 2;

  unsigned ahoff[4];
  int adst[4];
#pragma unroll
  for (int j = 0; j < 4; ++j) {
    int rb = j < 3 ? j * 64 + wv * 8 : 192 + (wv & 3) * 8;
    int r = rb + (l >> 3);
    int rc = r > 203 ? 203 : r;
    int hr = rc / 34, hc = rc - hr * 34;
    ahoff[j] = (unsigned)((bb * 34 + h0 + hr) * 34 + hc) * 512 + (((l & 7) ^ (r & 7)) << 3);
    adst[j] = rb;
  }
  // A-frag row base: frag m (0,1) = image row wr*2+m, col = l&31
  int pb32[2];
#pragma unroll
  for (int m = 0; m < 2; ++m) pb32[m] = ((wr << 1) + m) * 34 + (l & 31);

  // B direct-load lane base (bytes): co = bn*128 + wc*64 + n*32 + (l&31); ci16B = ks*16ci + (l>>5)*8ci
  const char* wtb = reinterpret_cast<const char*>(wt2);
  const unsigned nbase = (unsigned)(bn << 13) + (wc << 12) + ((l & 31) << 6) + ((l >> 5) << 4);

  f32x16 acc2[2][2];
#pragma unroll
  for (int n = 0; n < 2; ++n)
#pragma unroll
    for (int m = 0; m < 2; ++m) acc2[n][m] = (f32x16)0.f;

  bf16x8 fbk[2][2][2];  // [bank][ks][n], all indices literal after unroll

  auto stageA1 = [&](__hip_bfloat16* An, int j, int kn) {
    GLL(xsp + ahoff[j] + kn * 64, An + (adst[j] << 6));
  };
  auto loadB = [&](int bank, int t, int c) {
    const char* base = wtb + (size_t)(((t * 8 + c) * 2 + kg) << 15) + nbase;
#pragma unroll
    for (int ks = 0; ks < 2; ++ks)
#pragma unroll
      for (int n = 0; n < 2; ++n)
        fbk[bank][ks][n] = *reinterpret_cast<const bf16x8*>(base + (n << 11) + (ks << 5));
  };
  auto doTap = [&](int bank, const __hip_bfloat16* Aq, int dh, int dw) {
#pragma unroll
    for (int ks = 0; ks < 2; ++ks) {
      const int cb = (kg << 2) + (ks << 1) + (l >> 5);
      bf16x8 af[2];
#pragma unroll
      for (int m = 0; m < 2; ++m) {
        int p = pb32[m] + dh * 34 + dw;
        af[m] = *reinterpret_cast<const bf16x8*>(Aq + p * 64 + ((cb ^ (p & 7)) << 3));
      }
      __builtin_amdgcn_s_setprio(1);
#pragma unroll
      for (int n = 0; n < 2; ++n)
#pragma unroll
        for (int m = 0; m < 2; ++m)
          acc2[n][m] = __builtin_amdgcn_mfma_f32_32x32x16_bf16(fbk[bank][ks][n], af[m],
                                                               acc2[n][m], 0, 0, 0);
      __builtin_amdgcn_s_setprio(0);
    }
  };
  auto chunkBody = [&](int c, int P, bool stA, bool last) {
    const __hip_bfloat16* Aq = &As_[P][0];
    __hip_bfloat16* An = &As_[P ^ 1][0];
#pragma unroll
    for (int t = 0; t < 9; ++t) {
      if (!last || t < 8) loadB((P + t + 1) & 1, (t + 1) % 9, t < 8 ? c : c + 1);
      if (stA && t == 0) {
        stageA1(An, 0, c + 1); stageA1(An, 1, c + 1);
        stageA1(An, 2, c + 1); stageA1(An, 3, c + 1);
        __builtin_amdgcn_sched_barrier(0);
      }
      doTap((P + t) & 1, Aq, t / 3, t % 3);
    }
    if (!last) {
      asm volatile("s_waitcnt vmcnt(4)" ::: "memory");
      __builtin_amdgcn_s_barrier();
      __builtin_amdgcn_sched_barrier(0);
    }
  };

  // prologue
#pragma unroll
  for (int j = 0; j < 4; ++j) stageA1(&As_[0][0], j, 0);
  __builtin_amdgcn_sched_barrier(0);
  loadB(0, 0, 0);
  asm volatile("s_waitcnt vmcnt(4)" ::: "memory");
  __builtin_amdgcn_s_barrier();
  __builtin_amdgcn_sched_barrier(0);

#pragma unroll 1
  for (int kp = 0; kp < 3; ++kp) {
    chunkBody(2 * kp, 0, true, false);
    chunkBody(2 * kp + 1, 1, true, false);
  }
  chunkBody(6, 0, true, false);
  chunkBody(7, 1, false, true);

  // ---- cross-kg reduction ----
  __syncthreads();
  if (kg == 1) {
#pragma unroll
    for (int n = 0; n < 2; ++n)
#pragma unroll
      for (int m = 0; m < 2; ++m)
        *reinterpret_cast<f32x16*>(red + ((((n * 2 + m) * 4 + (wv & 3)) * 64 + l) << 4)) =
            acc2[n][m];
  }
  __syncthreads();
  if (kg == 0) {
    const int pixb = ((bm & 7) << 7) + (wr << 6) + (l & 31);
    const int cob = (bn << 7) + (wc << 6) + ((l >> 5) << 2);
    float* ob = out + ((size_t)bb << 19);
    const float* drow = dmod + bb * 512;
#pragma unroll
    for (int n = 0; n < 2; ++n) {
#pragma unroll
      for (int m = 0; m < 2; ++m) {
        f32x16 v = acc2[n][m] +
                   *reinterpret_cast<const f32x16*>(red + ((((n * 2 + m) * 4 + wv) * 64 + l) << 4));
        const int pix = pixb + (m << 5);
#pragma unroll
        for (int r = 0; r < 16; ++r) {
          const int co = cob + (n << 5) + (r & 3) + ((r >> 2) << 3);
          ob[((unsigned)co << 10) + pix] = v[r] * drow[co];
        }
      }
    }
  }
}

extern "C" void kernel_launch(void* const* d_in, const int* in_sizes, int n_in,
                              void* d_out, int out_size, void* d_ws, size_t ws_size,
                              hipStream_t stream) {
  (void)in_sizes; (void)n_in; (void)out_size; (void)ws_size;
  const float* x = (const float*)d_in[0];       // [8,512,32,32]
  const float* y = (const float*)d_in[1];       // [8,512]
  const float* w = (const float*)d_in[2];       // [512,512,3,3]
  const float* mw = (const float*)d_in[3];      // [512,512]
  const float* bias = (const float*)d_in[4];    // [512]
  float* out = (float*)d_out;                   // [8,512,32,32]

  char* ws = (char*)d_ws;
  float* s = (float*)(ws + 0);                  // 16 KB
  float* dmod = (float*)(ws + 16384);           // 16 KB
  float* wsq = (float*)(ws + 32768);            // 1 MB
  __hip_bfloat16* wt2 = (__hip_bfloat16*)(ws + 1081344);   // 4.5 MB
  __hip_bfloat16* xsp = (__hip_bfloat16*)(ws + 5799936);   // 9.03 MB

  prep_kernel<<<1416, 256, 0, stream>>>(w, y, mw, bias, wt2, wsq, s, xsp);
  xsdem_kernel<<<2176, 256, 0, stream>>>(x, s, wsq, xsp, dmod);
  conv_kernel<<<256, 512, 0, stream>>>(xsp, wt2, dmod, out);
}

// Round 15
// 59.130 us; speedup vs baseline: 1.0545x; 1.0545x over previous
//
#include <hip/hip_runtime.h>
#include <hip/hip_bf16.h>

typedef float f32x4 __attribute__((ext_vector_type(4)));
typedef short bf16x8 __attribute__((ext_vector_type(8)));

#define LRELU_SLOPE 0.2f
#define SQRT2F 1.4142135623730951f
#define MODSCALE 0.044194173824159216f  // 512^-0.5

#define GLL(SRC, DST)                                                       \
  __builtin_amdgcn_global_load_lds(                                         \
      (const __attribute__((address_space(1))) unsigned int*)(SRC),         \
      (__attribute__((address_space(3))) unsigned int*)(DST), 16, 0, 0)

// ---------- kernel 1: fused prep: wprep (blocks 0..1023) + style (1024..1151)
//            + xsp border zero (1152..1415) ----------
// wt2 layout: [t][kchunk c(8)][kh(2)][co(512)][ci32] bf16 (slab = 32 KB).
__global__ __launch_bounds__(256) void prep_kernel(const float* __restrict__ w,
                                                   const float* __restrict__ y,
                                                   const float* __restrict__ mw,
                                                   const float* __restrict__ bias,
                                                   __hip_bfloat16* __restrict__ wt2,
                                                   float* __restrict__ wsq,
                                                   float* __restrict__ s,
                                                   __hip_bfloat16* __restrict__ xsp) {
  const int bid = blockIdx.x;
  const int tid = threadIdx.x;
  if (bid < 1024) {  // ---- weight prep ----
    int idx = bid * 256 + tid;  // co*512+ci
    int co = idx >> 9, ci = idx & 511;
    const float* p = w + (size_t)idx * 9;
    float v[9];
    float sq = 0.f;
#pragma unroll
    for (int t = 0; t < 9; ++t) {
      v[t] = p[t];
      sq += v[t] * v[t];
    }
    wsq[idx] = sq;
    int slabbase = ((ci >> 6) * 2 + ((ci >> 5) & 1)) * 16384 + co * 32 + (ci & 31);
#pragma unroll
    for (int t = 0; t < 9; ++t)
      wt2[t * 262144 + slabbase] = __float2bfloat16(v[t]);
  } else if (bid < 1152) {  // ---- style ----
    int l = tid & 63;
    int ci = (bid - 1024) * 4 + (tid >> 6);
    const float4* mwr = reinterpret_cast<const float4*>(mw + ci * 512);
    float4 m0 = mwr[2 * l], m1 = mwr[2 * l + 1];
    float acc[8];
#pragma unroll
    for (int b = 0; b < 8; ++b) {
      const float4* yr = reinterpret_cast<const float4*>(y + b * 512);
      float4 y0 = yr[2 * l], y1 = yr[2 * l + 1];
      acc[b] = m0.x * y0.x + m0.y * y0.y + m0.z * y0.z + m0.w * y0.w +
               m1.x * y1.x + m1.y * y1.y + m1.z * y1.z + m1.w * y1.w;
    }
#pragma unroll
    for (int off = 32; off > 0; off >>= 1) {
#pragma unroll
      for (int b = 0; b < 8; ++b) acc[b] += __shfl_xor(acc[b], off, 64);
    }
    if (l < 8) {
      float v = acc[l] * MODSCALE + bias[ci];
      v = v > 0.f ? v : LRELU_SLOPE * v;
      s[l * 512 + ci] = v * SQRT2F;
    }
  } else {  // ---- zero the 1-px halo border of xsp ----
    int i = (bid - 1152) * 256 + tid;
    int b = i / 8448;
    int r = i - b * 8448;
    int pos = r >> 6;
    int cj = (r & 63) << 3;
    int hr, hc;
    if (pos < 34) { hr = 0; hc = pos; }
    else if (pos < 68) { hr = 33; hc = pos - 34; }
    else if (pos < 100) { hr = pos - 67; hc = 0; }
    else { hr = pos - 99; hc = 33; }
    unsigned off = (unsigned)((b * 34 + hr) * 34 + hc) * 512 + cj;
    int4 z = {0, 0, 0, 0};
    *reinterpret_cast<int4*>(xsp + off) = z;
  }
}

// ---------- kernel 2: fused xs (blocks 0..2047) + demod (2048..2175) ----------
__global__ __launch_bounds__(256) void xsdem_kernel(const float* __restrict__ x,
                                                    const float* __restrict__ s,
                                                    const float* __restrict__ wsq,
                                                    __hip_bfloat16* __restrict__ xsp,
                                                    float* __restrict__ d) {
  const int bid = blockIdx.x;
  const int tid = threadIdx.x;
  if (bid < 2048) {
    int cc = bid & 7;
    int h = (bid >> 3) & 31;
    int b = bid >> 8;
    __shared__ __hip_bfloat16 tile[32][72];
    int cil = tid >> 2;
    int w0 = (tid & 3) * 8;
    int ci = cc * 64 + cil;
    const float* xp = x + (((size_t)(b * 512 + ci) * 32 + h) << 5) + w0;
    float sv = s[b * 512 + ci];
    float4 a0 = *reinterpret_cast<const float4*>(xp);
    float4 a1 = *reinterpret_cast<const float4*>(xp + 4);
    tile[w0 + 0][cil] = __float2bfloat16(a0.x * sv);
    tile[w0 + 1][cil] = __float2bfloat16(a0.y * sv);
    tile[w0 + 2][cil] = __float2bfloat16(a0.z * sv);
    tile[w0 + 3][cil] = __float2bfloat16(a0.w * sv);
    tile[w0 + 4][cil] = __float2bfloat16(a1.x * sv);
    tile[w0 + 5][cil] = __float2bfloat16(a1.y * sv);
    tile[w0 + 6][cil] = __float2bfloat16(a1.z * sv);
    tile[w0 + 7][cil] = __float2bfloat16(a1.w * sv);
    __syncthreads();
    int wloc = tid >> 3;
    int cj = (tid & 7) * 8;
    int4 v = *reinterpret_cast<const int4*>(&tile[wloc][cj]);
    unsigned off = (unsigned)((b * 34 + h + 1) * 34 + (wloc + 1)) * 512 + cc * 64 + cj;
    *reinterpret_cast<int4*>(xsp + off) = v;
  } else {
    int l = tid & 63;
    int co = (bid - 2048) * 4 + (tid >> 6);
    const float4* qr = reinterpret_cast<const float4*>(wsq + co * 512);
    float4 q0 = qr[2 * l], q1 = qr[2 * l + 1];
    float acc[8];
#pragma unroll
    for (int b = 0; b < 8; ++b) {
      const float4* sr = reinterpret_cast<const float4*>(s + b * 512);
      float4 s0 = sr[2 * l], s1 = sr[2 * l + 1];
      acc[b] = q0.x * s0.x * s0.x + q0.y * s0.y * s0.y + q0.z * s0.z * s0.z +
               q0.w * s0.w * s0.w + q1.x * s1.x * s1.x + q1.y * s1.y * s1.y +
               q1.z * s1.z * s1.z + q1.w * s1.w * s1.w;
    }
#pragma unroll
    for (int off = 32; off > 0; off >>= 1) {
#pragma unroll
      for (int b = 0; b < 8; ++b) acc[b] += __shfl_xor(acc[b], off, 64);
    }
    if (l < 8) d[l * 512 + co] = rsqrtf(acc[l] + 1e-8f);
  }
}

// ---------- kernel 3: conv — 128x64 tiles, 256 thr (4 waves), 2 blocks/CU ----------
// Wave (wr,wc): 64 pix x 32 co, acc[2][4] f32x4 (16x16x32). A-halo in LDS (dbuf),
// B direct global->reg (1 KB coalesced frags), double-banked 1 tap ahead.
// 1 barrier per K-chunk; independent co-resident block hides the drain.
__global__ __launch_bounds__(256, 2) void conv_kernel(const __hip_bfloat16* __restrict__ xsp,
                                                      const __hip_bfloat16* __restrict__ wt2,
                                                      const float* __restrict__ dmod,
                                                      float* __restrict__ out) {
  __shared__ __hip_bfloat16 As_[2][224 * 64];  // 2 x 28 KB (204 halo rows used)
  const int bid = blockIdx.x;  // 512 blocks
  const int xcd = bid & 7, slot = bid >> 3;    // XCD = batch
  const int bmq = slot >> 3;                   // 0..7 (m-tile within batch)
  const int bn = slot & 7;                     // 0..7 (64-co tile)
  const int bb = xcd;                          // batch
  const int tid = threadIdx.x;
  const int wv = tid >> 6;                     // 0..3
  const int l = tid & 63;
  const int wr = wv >> 1, wc = wv & 1;
  const int h0 = bmq << 2;                     // first output image row of tile

  // ---- A staging offsets (pre-swizzled global source); 7 GLL/wave cover 224 rows ----
  unsigned ahoff[7];
  int adst[7];
#pragma unroll
  for (int j = 0; j < 7; ++j) {
    int rb = j * 32 + wv * 8;
    int r = rb + (l >> 3);                     // 0..223
    int rc = r > 203 ? 203 : r;                // rows 204..223 = safe garbage
    int hr = rc / 34, hc = rc - hr * 34;
    ahoff[j] = (unsigned)((bb * 34 + h0 + hr) * 34 + hc) * 512 + (((l & 7) ^ (r & 7)) << 3);
    adst[j] = rb;
  }
  int pb[4];
#pragma unroll
  for (int m = 0; m < 4; ++m)
    pb[m] = ((wr << 1) + (m >> 1)) * 34 + ((m & 1) << 4) + (l & 15);

  // ---- B direct-load lane base (bytes): frag = [16 co][32 ci] = 1 KB contiguous ----
  const char* wtb = reinterpret_cast<const char*>(wt2);
  const unsigned nbase = (unsigned)(bn << 12) + (wc << 11) + ((l & 15) << 6) + ((l >> 4) << 4);

  f32x4 acc[2][4];
#pragma unroll
  for (int n = 0; n < 2; ++n)
#pragma unroll
    for (int m = 0; m < 4; ++m) acc[n][m] = (f32x4)0.f;

  bf16x8 fbk[2][2][2];  // [bank][kh][n] — all literal indices after unroll

  auto stageA1 = [&](__hip_bfloat16* An, int j, int kn) {
    GLL(xsp + ahoff[j] + kn * 64, An + (adst[j] << 6));
  };
  auto loadB = [&](int bank, int t, int c) {
#pragma unroll
    for (int kh = 0; kh < 2; ++kh) {
      const char* base = wtb + (size_t)(((t * 8 + c) * 2 + kh) << 15) + nbase;
#pragma unroll
      for (int n = 0; n < 2; ++n)
        fbk[bank][kh][n] = *reinterpret_cast<const bf16x8*>(base + (n << 10));
    }
  };
  auto doTap = [&](int bank, const __hip_bfloat16* Aq, int dh, int dw) {
#pragma unroll
    for (int kh = 0; kh < 2; ++kh) {
      const int cb = (kh << 2) + (l >> 4);
      bf16x8 af[4];
#pragma unroll
      for (int m = 0; m < 4; ++m) {
        int p = pb[m] + dh * 34 + dw;
        af[m] = *reinterpret_cast<const bf16x8*>(Aq + p * 64 + ((cb ^ (p & 7)) << 3));
      }
      __builtin_amdgcn_s_setprio(1);
#pragma unroll
      for (int n = 0; n < 2; ++n)
#pragma unroll
        for (int m = 0; m < 4; ++m)
          acc[n][m] = __builtin_amdgcn_mfma_f32_16x16x32_bf16(fbk[bank][kh][n], af[m],
                                                              acc[n][m], 0, 0, 0);
      __builtin_amdgcn_s_setprio(0);
    }
  };
  auto chunkBody = [&](int c, int P, bool stA, bool last) {
    const __hip_bfloat16* Aq = &As_[P][0];
    __hip_bfloat16* An = &As_[P ^ 1][0];
#pragma unroll
    for (int t = 0; t < 9; ++t) {
      if (!last || t < 8) loadB((P + t + 1) & 1, (t + 1) % 9, t < 8 ? c : c + 1);
      if (stA && t == 0) {
#pragma unroll
        for (int j = 0; j < 7; ++j) stageA1(An, j, c + 1);
        __builtin_amdgcn_sched_barrier(0);  // pin: A-stage before later B loads
      }
      doTap((P + t) & 1, Aq, t / 3, t % 3);
    }
    if (!last) {
      // queue tail: [..., A(c+1)x7 (older), B(0,c+1)x4] -> vmcnt(4) retires A
      asm volatile("s_waitcnt vmcnt(4)" ::: "memory");
      __builtin_amdgcn_s_barrier();
      __builtin_amdgcn_sched_barrier(0);
    }
  };

  // prologue: A halo chunk 0 (7 GLL), then B(0,0) into bank 0
#pragma unroll
  for (int j = 0; j < 7; ++j) stageA1(&As_[0][0], j, 0);
  __builtin_amdgcn_sched_barrier(0);
  loadB(0, 0, 0);
  asm volatile("s_waitcnt vmcnt(4)" ::: "memory");  // A staged (4 B loads may fly)
  __builtin_amdgcn_s_barrier();
  __builtin_amdgcn_sched_barrier(0);

#pragma unroll 1
  for (int kp = 0; kp < 3; ++kp) {  // chunks 0..5, parity compile-time
    chunkBody(2 * kp, 0, true, false);
    chunkBody(2 * kp + 1, 1, true, false);
  }
  chunkBody(6, 0, true, false);   // stages A halo for chunk 7
  chunkBody(7, 1, false, true);   // drain

  // ---- epilogue: direct store (no reduction needed) ----
  const int pixbase = (bmq << 7) + (wr << 6) + (l & 15);
  const int cob = (bn << 6) + (wc << 5) + ((l >> 4) << 2);
  float* ob = out + ((size_t)bb << 19);
  const float* drow = dmod + bb * 512;
#pragma unroll
  for (int n = 0; n < 2; ++n) {
#pragma unroll
    for (int jj = 0; jj < 4; ++jj) {
      const int co = cob + (n << 4) + jj;
      const float dv = drow[co];
      float* orow = ob + ((unsigned)co << 10) + pixbase;
#pragma unroll
      for (int m = 0; m < 4; ++m) orow[m << 4] = acc[n][m][jj] * dv;
    }
  }
}

extern "C" void kernel_launch(void* const* d_in, const int* in_sizes, int n_in,
                              void* d_out, int out_size, void* d_ws, size_t ws_size,
                              hipStream_t stream) {
  (void)in_sizes; (void)n_in; (void)out_size; (void)ws_size;
  const float* x = (const float*)d_in[0];       // [8,512,32,32]
  const float* y = (const float*)d_in[1];       // [8,512]
  const float* w = (const float*)d_in[2];       // [512,512,3,3]
  const float* mw = (const float*)d_in[3];      // [512,512]
  const float* bias = (const float*)d_in[4];    // [512]
  float* out = (float*)d_out;                   // [8,512,32,32]

  char* ws = (char*)d_ws;
  float* s = (float*)(ws + 0);                  // 16 KB
  float* dmod = (float*)(ws + 16384);           // 16 KB
  float* wsq = (float*)(ws + 32768);            // 1 MB
  __hip_bfloat16* wt2 = (__hip_bfloat16*)(ws + 1081344);   // 4.5 MB
  __hip_bfloat16* xsp = (__hip_bfloat16*)(ws + 5799936);   // 9.03 MB

  prep_kernel<<<1416, 256, 0, stream>>>(w, y, mw, bias, wt2, wsq, s, xsp);
  xsdem_kernel<<<2176, 256, 0, stream>>>(x, s, wsq, xsp, dmod);
  conv_kernel<<<512, 256, 0, stream>>>(xsp, wt2, dmod, out);
}